// Round 1
// baseline (102.506 us; speedup 1.0000x reference)
//
#include <hip/hip_runtime.h>
#include <cstdint>

#define NB 32
#define NROIS 8192
#define NGT 128
#define NALL (NROIS + NGT)   // 8320
#define NSAMP 512
#define KPOS 128
#define KNEG 384
#define BCAP 2048

// ---------------- Kernel 1: IoU matching ----------------
// One thread per (b, i in rois_all). GT boxes + areas + masks staged in LDS.
// Bit-exact replication of reference op order; contraction off so
// (area_a + area_b) - iy*ix cannot fuse into FMA.
__global__ __launch_bounds__(256) void k_match(
    const float* __restrict__ rois,   // B,NROIS,4
    const float* __restrict__ gt,     // B,NGT,4
    int* __restrict__ mword)          // B*NALL : bits0-7 col, bits8-9 val+2
{
  #pragma clang fp contract(off)
  __shared__ float sg[NGT * 4];
  __shared__ float sarea[NGT];
  __shared__ unsigned char smask[NGT];

  const int b = blockIdx.y;
  const int i = blockIdx.x * blockDim.x + threadIdx.x;

  for (int t = threadIdx.x; t < NGT * 4; t += blockDim.x)
    sg[t] = gt[b * NGT * 4 + t];
  __syncthreads();
  if (threadIdx.x < NGT) {
    const int g = threadIdx.x;
    float b0 = sg[g*4+0], b1 = sg[g*4+1], b2 = sg[g*4+2], b3 = sg[g*4+3];
    sarea[g] = (b2 - b0) * (b3 - b1);
    smask[g] = (b0 == -1.0f) & (b1 == -1.0f) & (b2 == -1.0f) & (b3 == -1.0f);
  }
  __syncthreads();

  if (i >= NALL) return;

  float a0, a1, a2, a3;
  if (i < NROIS) {
    const float* p = &rois[(size_t)(b * NROIS + i) * 4];
    a0 = p[0]; a1 = p[1]; a2 = p[2]; a3 = p[3];
  } else {
    const int g = i - NROIS;
    a0 = sg[g*4+0]; a1 = sg[g*4+1]; a2 = sg[g*4+2]; a3 = sg[g*4+3];
  }
  const float area_a = (a2 - a0) * (a3 - a1);
  const bool mask_a = (a0 == -1.0f) && (a1 == -1.0f) && (a2 == -1.0f) && (a3 == -1.0f);

  float best = -3.0e38f;
  int bcol = 0;
  for (int j = 0; j < NGT; ++j) {
    float b0 = sg[j*4+0], b1 = sg[j*4+1], b2 = sg[j*4+2], b3 = sg[j*4+3];
    float iy = fmaxf(fminf(a2, b2) - fmaxf(a0, b0), 0.0f);
    float ix = fmaxf(fminf(a3, b3) - fmaxf(a1, b1), 0.0f);
    float inter = iy * ix;
    float uni = (area_a + sarea[j]) - inter;
    float iou = inter / fmaxf(uni, 1e-8f);
    if (mask_a || smask[j]) iou = -1.0f;
    if (iou > best) { best = iou; bcol = j; }   // first-max (argmax semantics)
  }
  int val = (best >= 0.5f) ? 1 : ((best >= 0.0f) ? -1 : -2);
  mword[b * NALL + i] = bcol | ((val + 2) << 8);
}

// ---------------- Kernel 2: balanced sampling + final ordering ----------------
// One block per batch. Exact top-k (value desc, index asc) via histogram on
// uniform [0,1) noise + exact sort of the boundary bin. Then build sampled_idx:
// indicator-1 indices ascending, then indicator-0 indices ascending.
__global__ __launch_bounds__(256) void k_select(
    const int* __restrict__ mword,
    const float* __restrict__ noise,  // B,NALL,2
    int* __restrict__ sidx,           // B,NSAMP
    int* __restrict__ k1out)          // B
{
  const int b = blockIdx.x;
  const int tid = threadIdx.x;
  const int T = 256;

  __shared__ int counts[1024];
  __shared__ float bval[BCAP];
  __shared__ int bidx_[BCAP];
  __shared__ int bcnt;
  __shared__ int s_bstar, s_need, s_selall;
  __shared__ unsigned char ind[NALL];
  __shared__ int csum[257];

  for (int i = tid; i < NALL; i += T) ind[i] = 0;

  for (int phase = 0; phase < 2; ++phase) {
    const int want = (phase == 0) ? KPOS : KNEG;
    const int wantval = (phase == 0) ? 3 : 1;  // (matched_val+2): pos=3, neg=1

    for (int i = tid; i < 1024; i += T) counts[i] = 0;
    if (tid == 0) bcnt = 0;
    __syncthreads();

    for (int i = tid; i < NALL; i += T) {
      int w = mword[b * NALL + i];
      if (((w >> 8) & 3) == wantval) {
        float v = noise[(size_t)(b * NALL + i) * 2 + phase];
        int bin = (int)(v * 1024.0f);
        bin = bin < 0 ? 0 : (bin > 1023 ? 1023 : bin);
        atomicAdd(&counts[bin], 1);
      }
    }
    __syncthreads();

    if (tid == 0) {
      int cum = 0, bs = -1, above = 0, selall = 1;
      for (int bb = 1023; bb >= 0; --bb) {
        int nc = cum + counts[bb];
        if (nc >= want) { bs = bb; above = cum; selall = 0; break; }
        cum = nc;
      }
      s_bstar = bs; s_need = want - above; s_selall = selall;
    }
    __syncthreads();
    const int bstar = s_bstar;
    const int selall = s_selall;

    for (int i = tid; i < NALL; i += T) {
      int w = mword[b * NALL + i];
      if (((w >> 8) & 3) == wantval) {
        float v = noise[(size_t)(b * NALL + i) * 2 + phase];
        int bin = (int)(v * 1024.0f);
        bin = bin < 0 ? 0 : (bin > 1023 ? 1023 : bin);
        if (selall || bin > bstar) {
          ind[i] = 1;
        } else if (bin == bstar) {
          int p = atomicAdd(&bcnt, 1);
          if (p < BCAP) { bval[p] = v; bidx_[p] = i; }
        }
      }
    }
    __syncthreads();

    if (tid == 0 && !selall) {
      int cnt = bcnt; if (cnt > BCAP) cnt = BCAP;
      // insertion sort: score desc, index asc (deterministic total order)
      for (int x = 1; x < cnt; ++x) {
        float v = bval[x]; int id = bidx_[x];
        int y = x - 1;
        while (y >= 0 && (bval[y] < v || (bval[y] == v && bidx_[y] > id))) {
          bval[y+1] = bval[y]; bidx_[y+1] = bidx_[y]; --y;
        }
        bval[y+1] = v; bidx_[y+1] = id;
      }
      int need = s_need; if (need > cnt) need = cnt;
      for (int x = 0; x < need; ++x) ind[bidx_[x]] = 1;
    }
    __syncthreads();
  }

  // ---- build sampled_idx: ones ascending, then zeros ascending ----
  const int C = (NALL + T - 1) / T;  // 33
  const int start = tid * C;
  const int end = (start + C < NALL) ? (start + C) : NALL;
  int s = 0;
  for (int i = start; i < end; ++i) s += ind[i];
  csum[tid] = s;
  __syncthreads();
  if (tid == 0) {
    int acc = 0;
    for (int t2 = 0; t2 < T; ++t2) { int v = csum[t2]; csum[t2] = acc; acc += v; }
    csum[T] = acc;
  }
  __syncthreads();
  const int K1 = csum[T];
  if (tid == 0) k1out[b] = K1;
  int ones_before = csum[tid];
  const int nzero = NSAMP - K1;
  for (int i = start; i < end; ++i) {
    if (ind[i]) {
      sidx[b * NSAMP + ones_before] = i;
      ones_before++;
    } else {
      int zrank = i - ones_before;
      if (zrank < nzero) sidx[b * NSAMP + K1 + zrank] = i;
    }
  }
}

// ---------------- Kernel 3: gather + encode + write outputs ----------------
__global__ __launch_bounds__(256) void k_gather(
    const float* __restrict__ rois,
    const float* __restrict__ gt,
    const float* __restrict__ gtcls,   // B,NGT,1
    const int* __restrict__ mword,
    const int* __restrict__ sidx,
    const int* __restrict__ k1,
    float* __restrict__ out)
{
  #pragma clang fp contract(off)
  const int t = blockIdx.x * blockDim.x + threadIdx.x;
  if (t >= NB * NSAMP) return;
  const int b = t / NSAMP;
  const int s = t % NSAMP;
  const int idx = sidx[t];

  float a0, a1, a2, a3;
  if (idx < NROIS) {
    const float* p = &rois[(size_t)(b * NROIS + idx) * 4];
    a0 = p[0]; a1 = p[1]; a2 = p[2]; a3 = p[3];
  } else {
    const float* p = &gt[(size_t)(b * NGT + (idx - NROIS)) * 4];
    a0 = p[0]; a1 = p[1]; a2 = p[2]; a3 = p[3];
  }

  const int w = mword[b * NALL + idx];
  const int col = w & 0xFF;
  const int val = ((w >> 8) & 3) - 2;
  const bool pos = (val == 1);

  float e0 = 0.f, e1 = 0.f, e2 = 0.f, e3 = 0.f, cls = 0.f;
  if (pos) {
    const float* g = &gt[(size_t)(b * NGT + col) * 4];
    float b0 = g[0], b1 = g[1], b2 = g[2], b3 = g[3];
    float ah = a2 - a0, aw = a3 - a1;
    float acy = a0 + 0.5f * ah, acx = a1 + 0.5f * aw;
    float bh = b2 - b0, bw = b3 - b1;
    float bcy = b0 + 0.5f * bh, bcx = b1 + 0.5f * bw;
    e0 = ((bcy - acy) / ah) / 0.1f;
    e1 = ((bcx - acx) / aw) / 0.1f;
    e2 = logf(bh / ah) / 0.2f;
    e3 = logf(bw / aw) / 0.2f;
    cls = gtcls[b * NGT + col];
  }
  const float bweight = pos ? 1.0f : 0.0f;
  const float cweight = (s < k1[b]) ? 1.0f : 0.0f;

  float* o_rois = out;                          // NB*NSAMP*4
  float* o_enc  = out + (size_t)NB * NSAMP * 4; // NB*NSAMP*4
  float* o_bw   = out + (size_t)NB * NSAMP * 8;
  float* o_cls  = o_bw + (size_t)NB * NSAMP;
  float* o_cw   = o_cls + (size_t)NB * NSAMP;

  o_rois[t*4+0] = a0; o_rois[t*4+1] = a1; o_rois[t*4+2] = a2; o_rois[t*4+3] = a3;
  o_enc[t*4+0] = e0; o_enc[t*4+1] = e1; o_enc[t*4+2] = e2; o_enc[t*4+3] = e3;
  o_bw[t] = bweight;
  o_cls[t] = cls;
  o_cw[t] = cweight;
}

extern "C" void kernel_launch(void* const* d_in, const int* in_sizes, int n_in,
                              void* d_out, int out_size, void* d_ws, size_t ws_size,
                              hipStream_t stream) {
  const float* rois  = (const float*)d_in[0];
  const float* gt    = (const float*)d_in[1];
  const float* gtcls = (const float*)d_in[2];
  const float* noise = (const float*)d_in[3];
  float* out = (float*)d_out;

  uint8_t* ws = (uint8_t*)d_ws;
  int* mword = (int*)ws;                                    // NB*NALL ints
  int* sidx  = (int*)(ws + (size_t)NB * NALL * sizeof(int)); // NB*NSAMP ints
  int* k1    = sidx + NB * NSAMP;                           // NB ints

  dim3 g1((NALL + 255) / 256, NB);
  k_match<<<g1, 256, 0, stream>>>(rois, gt, mword);
  k_select<<<NB, 256, 0, stream>>>(mword, noise, sidx, k1);
  k_gather<<<(NB * NSAMP + 255) / 256, 256, 0, stream>>>(rois, gt, gtcls, mword, sidx, k1, out);
}

// Round 2
// 70.515 us; speedup vs baseline: 1.4537x; 1.4537x over previous
//
#include <hip/hip_runtime.h>
#include <cstdint>

#define NB 32
#define NROIS 8192
#define NGT 128
#define NALL (NROIS + NGT)   // 8320
#define NSAMP 512
#define KPOS 128
#define KNEG 384
#define BCAP 1024
#define TS 512               // k_select threads
#define RPT 2                // rois per thread in k_match

// ---------------- Kernel 1: IoU matching ----------------
// 2 rois/thread so the per-gt LDS reads (float4 + area) are amortized.
// Mask folded into area sentinel (-1). IEEE div + contract(off) for
// bit-exact match with the numpy reference comparisons.
__global__ __launch_bounds__(256) void k_match(
    const float* __restrict__ rois,   // B,NROIS,4
    const float* __restrict__ gt,     // B,NGT,4
    int* __restrict__ mword)          // B*NALL : bits0-7 col, bits8-9 val+2
{
  #pragma clang fp contract(off)
  __shared__ float4 sg[NGT];
  __shared__ float sam[NGT];          // area, or -1.0 sentinel if masked

  const int b = blockIdx.y;
  if (threadIdx.x < NGT) {
    float4 g = reinterpret_cast<const float4*>(gt)[b * NGT + threadIdx.x];
    sg[threadIdx.x] = g;
    float area = (g.z - g.x) * (g.w - g.y);
    bool m = (g.x == -1.0f) && (g.y == -1.0f) && (g.z == -1.0f) && (g.w == -1.0f);
    sam[threadIdx.x] = m ? -1.0f : area;
  }
  __syncthreads();

  const int base = blockIdx.x * (256 * RPT);
  float a0[RPT], a1[RPT], a2[RPT], a3[RPT], aar[RPT];
  bool ma[RPT], act[RPT];
  float best[RPT];
  int bcol[RPT];

  #pragma unroll
  for (int r = 0; r < RPT; ++r) {
    const int i = base + r * 256 + threadIdx.x;
    act[r] = (i < NALL);
    best[r] = -3.0e38f; bcol[r] = 0;
    a0[r] = a1[r] = a2[r] = a3[r] = 0.0f; aar[r] = 0.0f; ma[r] = false;
    if (act[r]) {
      float4 A = (i < NROIS)
        ? reinterpret_cast<const float4*>(rois)[b * NROIS + i]
        : sg[i - NROIS];
      a0[r] = A.x; a1[r] = A.y; a2[r] = A.z; a3[r] = A.w;
      aar[r] = (A.z - A.x) * (A.w - A.y);
      ma[r] = (A.x == -1.0f) && (A.y == -1.0f) && (A.z == -1.0f) && (A.w == -1.0f);
    }
  }

  for (int j = 0; j < NGT; ++j) {
    const float4 g = sg[j];
    const float sa = sam[j];
    const bool mj = (sa < 0.0f);
    const float ab = mj ? 0.0f : sa;
    #pragma unroll
    for (int r = 0; r < RPT; ++r) {
      float iy = fmaxf(fminf(a2[r], g.z) - fmaxf(a0[r], g.x), 0.0f);
      float ix = fmaxf(fminf(a3[r], g.w) - fmaxf(a1[r], g.y), 0.0f);
      float inter = iy * ix;
      float uni = (aar[r] + ab) - inter;
      float iou = inter / fmaxf(uni, 1e-8f);
      if (ma[r] || mj) iou = -1.0f;
      if (iou > best[r]) { best[r] = iou; bcol[r] = j; }   // first-max argmax
    }
  }

  #pragma unroll
  for (int r = 0; r < RPT; ++r) {
    if (act[r]) {
      const int i = base + r * 256 + threadIdx.x;
      int val = (best[r] >= 0.5f) ? 1 : ((best[r] >= 0.0f) ? -1 : -2);
      mword[b * NALL + i] = bcol[r] | ((val + 2) << 8);
    }
  }
}

// ---------------- Kernel 2: balanced sampling + ordering + gather ----------------
// One block of 512 threads per batch. All previously-serial sections are
// parallel: Hillis-Steele suffix scan over the 1024 noise-histogram bins
// (2 bins/thread) to find the boundary bin, parallel prefix scan for the
// final (ones-ascending, zeros-ascending) ordering, and a fused gather
// (one sample per thread). Only the boundary-bin sort (expected ~8 elems,
// uniform noise) stays serial.
__global__ __launch_bounds__(TS) void k_select(
    const int* __restrict__ mword,
    const float* __restrict__ noise,  // B,NALL,2
    const float* __restrict__ rois,
    const float* __restrict__ gt,
    const float* __restrict__ gtcls,  // B,NGT,1
    float* __restrict__ out)
{
  #pragma clang fp contract(off)
  const int b = blockIdx.x;
  const int tid = threadIdx.x;

  __shared__ int counts[1024];
  __shared__ int ssum[TS];
  __shared__ float bval[BCAP];
  __shared__ int bidx_[BCAP];
  __shared__ int bcnt;
  __shared__ int s_bstar, s_need;
  __shared__ unsigned char codes[NALL];
  __shared__ unsigned char ind[NALL];
  __shared__ unsigned short sbin[NALL];  // bin+1, or 0 if not candidate
  __shared__ unsigned short sorder[NSAMP];

  for (int i = tid; i < NALL; i += TS) {
    codes[i] = (unsigned char)((mword[b * NALL + i] >> 8) & 3);
    ind[i] = 0;
  }
  __syncthreads();

  for (int phase = 0; phase < 2; ++phase) {
    const int want = (phase == 0) ? KPOS : KNEG;
    const unsigned char wantc = (phase == 0) ? 3 : 1;  // pos=3, neg=1

    counts[tid] = 0;
    counts[tid + TS] = 0;
    if (tid == 0) bcnt = 0;
    __syncthreads();

    // histogram on uniform [0,1) noise; remember each candidate's bin
    for (int i = tid; i < NALL; i += TS) {
      unsigned short sb = 0;
      if (codes[i] == wantc) {
        float v = noise[((size_t)(b * NALL + i)) * 2 + phase];
        int bin = (int)(v * 1024.0f);
        bin = bin < 0 ? 0 : (bin > 1023 ? 1023 : bin);
        atomicAdd(&counts[bin], 1);
        sb = (unsigned short)(bin + 1);
      }
      sbin[i] = sb;
    }
    __syncthreads();

    // parallel suffix scan over bins (thread t owns bins 2t, 2t+1)
    const int c0 = counts[2 * tid], c1 = counts[2 * tid + 1];
    ssum[tid] = c0 + c1;
    __syncthreads();
    for (int off = 1; off < TS; off <<= 1) {
      int v = ssum[tid] + ((tid + off < TS) ? ssum[tid + off] : 0);
      __syncthreads();
      ssum[tid] = v;
      __syncthreads();
    }
    const int total = ssum[0];
    const bool selall = (total < want);
    if (!selall) {
      const int above_hi = (tid + 1 < TS) ? ssum[tid + 1] : 0;  // sum of bins > 2t+1
      if (ssum[tid] >= want && above_hi < want) {               // unique thread
        if (above_hi + c1 >= want) { s_bstar = 2 * tid + 1; s_need = want - above_hi; }
        else                       { s_bstar = 2 * tid;     s_need = want - (above_hi + c1); }
      }
    }
    __syncthreads();
    const int bstar = selall ? -1 : s_bstar;

    // mark: bins above boundary all selected; boundary bin collected
    for (int i = tid; i < NALL; i += TS) {
      const int sb = sbin[i];
      if (sb) {
        const int bin = sb - 1;
        if (selall || bin > bstar) {
          ind[i] = 1;
        } else if (bin == bstar) {
          int p = atomicAdd(&bcnt, 1);
          if (p < BCAP) {
            bval[p] = noise[((size_t)(b * NALL + i)) * 2 + phase];
            bidx_[p] = i;
          }
        }
      }
    }
    __syncthreads();

    // exact sort of the boundary bin: value desc, index asc (top_k tie-break)
    if (tid == 0 && !selall) {
      int cnt = bcnt; if (cnt > BCAP) cnt = BCAP;
      for (int x = 1; x < cnt; ++x) {
        float v = bval[x]; int id = bidx_[x];
        int y = x - 1;
        while (y >= 0 && (bval[y] < v || (bval[y] == v && bidx_[y] > id))) {
          bval[y + 1] = bval[y]; bidx_[y + 1] = bidx_[y]; --y;
        }
        bval[y + 1] = v; bidx_[y + 1] = id;
      }
      int need = s_need; if (need > cnt) need = cnt;
      for (int x = 0; x < need; ++x) ind[bidx_[x]] = 1;
    }
    __syncthreads();
  }

  // ---- ordering: ones ascending then zeros ascending (top_k of 0/1) ----
  const int C = (NALL + TS - 1) / TS;  // 17
  const int start = tid * C;
  const int end = (start + C < NALL) ? (start + C) : NALL;
  int cnt1 = 0;
  for (int i = start; i < end; ++i) cnt1 += ind[i];
  ssum[tid] = cnt1;
  __syncthreads();
  for (int off = 1; off < TS; off <<= 1) {
    int v = ssum[tid] + ((tid >= off) ? ssum[tid - off] : 0);
    __syncthreads();
    ssum[tid] = v;
    __syncthreads();
  }
  const int K1 = ssum[TS - 1];
  int ones_before = ssum[tid] - cnt1;
  const int nzero = NSAMP - K1;
  for (int i = start; i < end; ++i) {
    if (ind[i]) {
      sorder[ones_before] = (unsigned short)i;
      ones_before++;
    } else {
      const int zrank = i - ones_before;
      if (zrank < nzero) sorder[K1 + zrank] = (unsigned short)i;
    }
  }
  __syncthreads();

  // ---- fused gather + encode + write (one sample per thread) ----
  {
    const int s = tid;
    const int idx = sorder[s];
    const size_t t = (size_t)b * NSAMP + s;

    float4 A = (idx < NROIS)
      ? reinterpret_cast<const float4*>(rois)[b * NROIS + idx]
      : reinterpret_cast<const float4*>(gt)[b * NGT + (idx - NROIS)];

    const int w = mword[b * NALL + idx];
    const int col = w & 0xFF;
    const bool pos = (((w >> 8) & 3) == 3);

    float e0 = 0.f, e1 = 0.f, e2 = 0.f, e3 = 0.f, cls = 0.f;
    if (pos) {
      float4 G = reinterpret_cast<const float4*>(gt)[b * NGT + col];
      float ah = A.z - A.x, aw = A.w - A.y;
      float acy = A.x + 0.5f * ah, acx = A.y + 0.5f * aw;
      float bh = G.z - G.x, bw = G.w - G.y;
      float bcy = G.x + 0.5f * bh, bcx = G.y + 0.5f * bw;
      e0 = ((bcy - acy) / ah) / 0.1f;
      e1 = ((bcx - acx) / aw) / 0.1f;
      e2 = logf(bh / ah) / 0.2f;
      e3 = logf(bw / aw) / 0.2f;
      cls = gtcls[b * NGT + col];
    }

    float* o_rois = out;                           // NB*NSAMP*4
    float* o_enc  = out + (size_t)NB * NSAMP * 4;  // NB*NSAMP*4
    float* o_bw   = out + (size_t)NB * NSAMP * 8;
    float* o_cls  = o_bw + (size_t)NB * NSAMP;
    float* o_cw   = o_cls + (size_t)NB * NSAMP;

    reinterpret_cast<float4*>(o_rois)[t] = A;
    float4 E; E.x = e0; E.y = e1; E.z = e2; E.w = e3;
    reinterpret_cast<float4*>(o_enc)[t] = E;
    o_bw[t]  = pos ? 1.0f : 0.0f;
    o_cls[t] = cls;
    o_cw[t]  = (s < K1) ? 1.0f : 0.0f;
  }
}

extern "C" void kernel_launch(void* const* d_in, const int* in_sizes, int n_in,
                              void* d_out, int out_size, void* d_ws, size_t ws_size,
                              hipStream_t stream) {
  const float* rois  = (const float*)d_in[0];
  const float* gt    = (const float*)d_in[1];
  const float* gtcls = (const float*)d_in[2];
  const float* noise = (const float*)d_in[3];
  float* out = (float*)d_out;

  int* mword = (int*)d_ws;  // NB*NALL ints

  dim3 g1((NALL + 256 * RPT - 1) / (256 * RPT), NB);  // (17, 32)
  k_match<<<g1, 256, 0, stream>>>(rois, gt, mword);
  k_select<<<NB, TS, 0, stream>>>(mword, noise, rois, gt, gtcls, out);
}

// Round 3
// 62.505 us; speedup vs baseline: 1.6400x; 1.1281x over previous
//
#include <hip/hip_runtime.h>
#include <cstdint>

#define NB 32
#define NROIS 8192
#define NGT 128
#define NALL (NROIS + NGT)   // 8320
#define NSAMP 512
#define KPOS 128
#define KNEG 384
#define BCAP 1024
#define TS 512               // k_select threads
#define JC 4                 // independent gt chains per thread (ILP)
#define JL (NGT / JC)        // 32

// ---------------- Kernel 1: IoU matching ----------------
// One roi per thread; the 128-gt argmax is split into JC=4 interleaved
// chains (chain c owns j in [c*JL,(c+1)*JL), ascending) so there are 4
// independent dependence chains in flight. In-thread combine in ascending
// chain order preserves exact first-max argmax semantics. IEEE div +
// contract(off) keeps iou bit-exact vs the numpy reference.
__global__ __launch_bounds__(256) void k_match(
    const float* __restrict__ rois,   // B,NROIS,4
    const float* __restrict__ gt,     // B,NGT,4
    int* __restrict__ mword)          // B*NALL : bits0-7 col, bits8-9 val+2
{
  #pragma clang fp contract(off)
  __shared__ float4 sg[NGT];
  __shared__ float sab[NGT];           // area (0 if masked)
  __shared__ unsigned char smk[NGT];   // masked flag

  const int b = blockIdx.y;
  const int tid = threadIdx.x;
  if (tid < NGT) {
    float4 g = reinterpret_cast<const float4*>(gt)[b * NGT + tid];
    sg[tid] = g;
    bool m = (g.x == -1.0f) && (g.y == -1.0f) && (g.z == -1.0f) && (g.w == -1.0f);
    sab[tid] = m ? 0.0f : (g.z - g.x) * (g.w - g.y);
    smk[tid] = m;
  }
  __syncthreads();

  const int i = blockIdx.x * 256 + tid;
  if (i >= NALL) return;

  float4 A = (i < NROIS)
    ? reinterpret_cast<const float4*>(rois)[b * NROIS + i]
    : sg[i - NROIS];
  const float aar = (A.z - A.x) * (A.w - A.y);
  const bool ma = (A.x == -1.0f) && (A.y == -1.0f) && (A.z == -1.0f) && (A.w == -1.0f);

  float best[JC];
  int bcol[JC];
  #pragma unroll
  for (int c = 0; c < JC; ++c) { best[c] = -3.0e38f; bcol[c] = c * JL; }

  for (int jj = 0; jj < JL; ++jj) {
    #pragma unroll
    for (int c = 0; c < JC; ++c) {
      const int j = c * JL + jj;
      const float4 g = sg[j];
      const float ab = sab[j];
      const bool mj = (smk[j] != 0);
      float iy = fmaxf(fminf(A.z, g.z) - fmaxf(A.x, g.x), 0.0f);
      float ix = fmaxf(fminf(A.w, g.w) - fmaxf(A.y, g.y), 0.0f);
      float inter = iy * ix;
      float uni = (aar + ab) - inter;
      float iou = inter / fmaxf(uni, 1e-8f);
      if (ma || mj) iou = -1.0f;
      if (iou > best[c]) { best[c] = iou; bcol[c] = j; }  // first-max in-chain
    }
  }

  float bb = best[0];
  int cc = bcol[0];
  #pragma unroll
  for (int c = 1; c < JC; ++c) {
    if (best[c] > bb) { bb = best[c]; cc = bcol[c]; }     // lower chain wins ties
  }

  int val = (bb >= 0.5f) ? 1 : ((bb >= 0.0f) ? -1 : -2);
  mword[b * NALL + i] = cc | ((val + 2) << 8);
}

// ---------------- shfl-based block inclusive scan (TS=512, 8 waves) ----------
__device__ __forceinline__ int block_incl_scan(int v, int tid, int* wsum) {
  __syncthreads();  // protect wsum reuse across consecutive calls
  int s = v;
  #pragma unroll
  for (int off = 1; off < 64; off <<= 1) {
    int u = __shfl_up(s, off);
    if ((tid & 63) >= off) s += u;
  }
  const int wid = tid >> 6;
  if ((tid & 63) == 63) wsum[wid] = s;
  __syncthreads();
  if (wid == 0) {
    const int lane = tid & 63;
    int w = (lane < (TS >> 6)) ? wsum[lane] : 0;
    #pragma unroll
    for (int off = 1; off < (TS >> 6); off <<= 1) {
      int u = __shfl_up(w, off);
      if (lane >= off) w += u;
    }
    if (lane < (TS >> 6)) wsum[lane] = w;
  }
  __syncthreads();
  return s + (wid ? wsum[wid - 1] : 0);
}

// ---------------- Kernel 2: balanced sampling + ordering + gather ----------------
__global__ __launch_bounds__(TS) void k_select(
    const int* __restrict__ mword,
    const float* __restrict__ noise,  // B,NALL,2
    const float* __restrict__ rois,
    const float* __restrict__ gt,
    const float* __restrict__ gtcls,  // B,NGT,1
    float* __restrict__ out)
{
  #pragma clang fp contract(off)
  const int b = blockIdx.x;
  const int tid = threadIdx.x;

  __shared__ int counts[1024];
  __shared__ int wsum[TS >> 6];
  __shared__ int s_total;
  __shared__ float bval[BCAP];
  __shared__ int bidx_[BCAP];
  __shared__ int bcnt;
  __shared__ int s_bstar, s_need;
  __shared__ unsigned char codes[NALL];
  __shared__ unsigned char ind[NALL];
  __shared__ unsigned short sbin[NALL];  // bin+1, or 0 if not candidate
  __shared__ unsigned short sorder[NSAMP];

  for (int i = tid; i < NALL; i += TS) {
    codes[i] = (unsigned char)((mword[b * NALL + i] >> 8) & 3);
    ind[i] = 0;
  }
  __syncthreads();

  for (int phase = 0; phase < 2; ++phase) {
    const int want = (phase == 0) ? KPOS : KNEG;
    const unsigned char wantc = (phase == 0) ? 3 : 1;  // pos=3, neg=1

    counts[tid] = 0;
    counts[tid + TS] = 0;
    if (tid == 0) bcnt = 0;
    __syncthreads();

    // histogram on uniform [0,1) noise; remember each candidate's bin
    for (int i = tid; i < NALL; i += TS) {
      unsigned short sb = 0;
      if (codes[i] == wantc) {
        float v = noise[((size_t)(b * NALL + i)) * 2 + phase];
        int bin = (int)(v * 1024.0f);
        bin = bin < 0 ? 0 : (bin > 1023 ? 1023 : bin);
        atomicAdd(&counts[bin], 1);
        sb = (unsigned short)(bin + 1);
      }
      sbin[i] = sb;
    }
    __syncthreads();

    // thread t owns bins 2t,2t+1; inclusive scan -> suffix algebra
    const int c0 = counts[2 * tid], c1 = counts[2 * tid + 1];
    const int incl = block_incl_scan(c0 + c1, tid, wsum);
    if (tid == TS - 1) s_total = incl;
    __syncthreads();
    const int total = s_total;
    const bool selall = (total < want);
    if (!selall) {
      const int above_hi = total - incl;        // sum of bins > 2t+1
      const int suff = above_hi + c0 + c1;      // sum of bins >= 2t
      if (suff >= want && above_hi < want) {    // unique boundary thread
        if (above_hi + c1 >= want) { s_bstar = 2 * tid + 1; s_need = want - above_hi; }
        else                       { s_bstar = 2 * tid;     s_need = want - (above_hi + c1); }
      }
    }
    __syncthreads();
    const int bstar = selall ? -1 : s_bstar;

    // mark: bins above boundary all selected; boundary bin collected
    for (int i = tid; i < NALL; i += TS) {
      const int sb = sbin[i];
      if (sb) {
        const int bin = sb - 1;
        if (selall || bin > bstar) {
          ind[i] = 1;
        } else if (bin == bstar) {
          int p = atomicAdd(&bcnt, 1);
          if (p < BCAP) {
            bval[p] = noise[((size_t)(b * NALL + i)) * 2 + phase];
            bidx_[p] = i;
          }
        }
      }
    }
    __syncthreads();

    // exact sort of the boundary bin: value desc, index asc (top_k tie-break)
    if (tid == 0 && !selall) {
      int cnt = bcnt; if (cnt > BCAP) cnt = BCAP;
      for (int x = 1; x < cnt; ++x) {
        float v = bval[x]; int id = bidx_[x];
        int y = x - 1;
        while (y >= 0 && (bval[y] < v || (bval[y] == v && bidx_[y] > id))) {
          bval[y + 1] = bval[y]; bidx_[y + 1] = bidx_[y]; --y;
        }
        bval[y + 1] = v; bidx_[y + 1] = id;
      }
      int need = s_need; if (need > cnt) need = cnt;
      for (int x = 0; x < need; ++x) ind[bidx_[x]] = 1;
    }
    __syncthreads();
  }

  // ---- ordering: ones ascending then zeros ascending (top_k of 0/1) ----
  const int C = (NALL + TS - 1) / TS;  // 17
  const int start = tid * C;
  const int end = (start + C < NALL) ? (start + C) : NALL;
  int cnt1 = 0;
  for (int i = start; i < end; ++i) cnt1 += ind[i];
  const int incl1 = block_incl_scan(cnt1, tid, wsum);
  if (tid == TS - 1) s_total = incl1;
  __syncthreads();
  const int K1 = s_total;
  int ones_before = incl1 - cnt1;
  const int nzero = NSAMP - K1;
  for (int i = start; i < end; ++i) {
    if (ind[i]) {
      sorder[ones_before] = (unsigned short)i;
      ones_before++;
    } else {
      const int zrank = i - ones_before;
      if (zrank < nzero) sorder[K1 + zrank] = (unsigned short)i;
    }
  }
  __syncthreads();

  // ---- fused gather + encode + write (one sample per thread) ----
  {
    const int s = tid;
    const int idx = sorder[s];
    const size_t t = (size_t)b * NSAMP + s;

    float4 A = (idx < NROIS)
      ? reinterpret_cast<const float4*>(rois)[b * NROIS + idx]
      : reinterpret_cast<const float4*>(gt)[b * NGT + (idx - NROIS)];

    const int w = mword[b * NALL + idx];
    const int col = w & 0xFF;
    const bool pos = (((w >> 8) & 3) == 3);

    float e0 = 0.f, e1 = 0.f, e2 = 0.f, e3 = 0.f, cls = 0.f;
    if (pos) {
      float4 G = reinterpret_cast<const float4*>(gt)[b * NGT + col];
      float ah = A.z - A.x, aw = A.w - A.y;
      float acy = A.x + 0.5f * ah, acx = A.y + 0.5f * aw;
      float bh = G.z - G.x, bw = G.w - G.y;
      float bcy = G.x + 0.5f * bh, bcx = G.y + 0.5f * bw;
      e0 = ((bcy - acy) / ah) / 0.1f;
      e1 = ((bcx - acx) / aw) / 0.1f;
      e2 = logf(bh / ah) / 0.2f;
      e3 = logf(bw / aw) / 0.2f;
      cls = gtcls[b * NGT + col];
    }

    float* o_rois = out;                           // NB*NSAMP*4
    float* o_enc  = out + (size_t)NB * NSAMP * 4;  // NB*NSAMP*4
    float* o_bw   = out + (size_t)NB * NSAMP * 8;
    float* o_cls  = o_bw + (size_t)NB * NSAMP;
    float* o_cw   = o_cls + (size_t)NB * NSAMP;

    reinterpret_cast<float4*>(o_rois)[t] = A;
    float4 E; E.x = e0; E.y = e1; E.z = e2; E.w = e3;
    reinterpret_cast<float4*>(o_enc)[t] = E;
    o_bw[t]  = pos ? 1.0f : 0.0f;
    o_cls[t] = cls;
    o_cw[t]  = (s < K1) ? 1.0f : 0.0f;
  }
}

extern "C" void kernel_launch(void* const* d_in, const int* in_sizes, int n_in,
                              void* d_out, int out_size, void* d_ws, size_t ws_size,
                              hipStream_t stream) {
  const float* rois  = (const float*)d_in[0];
  const float* gt    = (const float*)d_in[1];
  const float* gtcls = (const float*)d_in[2];
  const float* noise = (const float*)d_in[3];
  float* out = (float*)d_out;

  int* mword = (int*)d_ws;  // NB*NALL ints

  dim3 g1((NALL + 255) / 256, NB);  // (33, 32) = 1056 blocks
  k_match<<<g1, 256, 0, stream>>>(rois, gt, mword);
  k_select<<<NB, TS, 0, stream>>>(mword, noise, rois, gt, gtcls, out);
}

// Round 4
// 58.786 us; speedup vs baseline: 1.7437x; 1.0633x over previous
//
#include <hip/hip_runtime.h>
#include <cstdint>

#define NB 32
#define NROIS 8192
#define NGT 128
#define NALL (NROIS + NGT)   // 8320
#define NSAMP 512
#define KPOS 128
#define KNEG 384
#define BCAP 1024
#define TS 512               // k_select threads
#define CH 17                // ceil(NALL/TS)
#define JC 4                 // independent gt chains per thread (ILP)
#define JL (NGT / JC)        // 32

// ---------------- Kernel 1: IoU matching ----------------
// One roi per thread; 128-gt argmax split into JC=4 interleaved chains.
// gt boxes + areas staged in LDS; jj-loop unrolled so all LDS offsets are
// immediates (no per-access address VALU). Mask handling is hoisted out of
// the hot loop: a maskless fast path runs unless any box is [-1,-1,-1,-1]
// (never true for this data; slow path preserves exact semantics).
template <bool MASKED>
__device__ __forceinline__ void match_loop(
    const float4* __restrict__ sg, const float* __restrict__ sab,
    const unsigned char* __restrict__ smk,
    const float4 A, const float aar, const bool ma,
    float* best, int* bcol)
{
  #pragma clang fp contract(off)
  #pragma unroll 8
  for (int jj = 0; jj < JL; ++jj) {
    #pragma unroll
    for (int c = 0; c < JC; ++c) {
      const int j = c * JL + jj;
      const float4 g = sg[j];
      const float ab = sab[j];
      float iy = fmaxf(fminf(A.z, g.z) - fmaxf(A.x, g.x), 0.0f);
      float ix = fmaxf(fminf(A.w, g.w) - fmaxf(A.y, g.y), 0.0f);
      float inter = iy * ix;
      float uni = (aar + ab) - inter;
      float iou = inter / fmaxf(uni, 1e-8f);
      if (MASKED) {
        if (ma || (smk[j] != 0)) iou = -1.0f;
      }
      if (iou > best[c]) { best[c] = iou; bcol[c] = j; }  // first-max in-chain
    }
  }
}

__global__ __launch_bounds__(256) void k_match(
    const float* __restrict__ rois,   // B,NROIS,4
    const float* __restrict__ gt,     // B,NGT,4
    int* __restrict__ mword)          // B*NALL : bits0-7 col, bits8-9 val+2
{
  #pragma clang fp contract(off)
  __shared__ float4 sg[NGT];
  __shared__ float sab[NGT];           // plain area
  __shared__ unsigned char smk[NGT];   // masked flag (slow path only)
  __shared__ int s_anymask;

  const int b = blockIdx.y;
  const int tid = threadIdx.x;

  bool mflag = false;
  if (tid < NGT) {
    float4 g = reinterpret_cast<const float4*>(gt)[b * NGT + tid];
    sg[tid] = g;
    sab[tid] = (g.z - g.x) * (g.w - g.y);
    mflag = (g.x == -1.0f) && (g.y == -1.0f) && (g.z == -1.0f) && (g.w == -1.0f);
    smk[tid] = mflag;
  }
  if (tid == 0) s_anymask = 0;
  __syncthreads();
  if (mflag) atomicOr(&s_anymask, 1);
  __syncthreads();

  const int i = blockIdx.x * 256 + tid;
  if (i >= NALL) return;

  float4 A = (i < NROIS)
    ? reinterpret_cast<const float4*>(rois)[b * NROIS + i]
    : sg[i - NROIS];
  const float aar = (A.z - A.x) * (A.w - A.y);
  const bool ma = (A.x == -1.0f) && (A.y == -1.0f) && (A.z == -1.0f) && (A.w == -1.0f);

  float best[JC];
  int bcol[JC];
  #pragma unroll
  for (int c = 0; c < JC; ++c) { best[c] = -3.0e38f; bcol[c] = c * JL; }

  if (s_anymask == 0 && __ballot(ma) == 0ULL) {
    match_loop<false>(sg, sab, smk, A, aar, ma, best, bcol);
  } else {
    match_loop<true>(sg, sab, smk, A, aar, ma, best, bcol);
  }

  float bb = best[0];
  int cc = bcol[0];
  #pragma unroll
  for (int c = 1; c < JC; ++c) {
    if (best[c] > bb) { bb = best[c]; cc = bcol[c]; }     // lower chain wins ties
  }

  int val = (bb >= 0.5f) ? 1 : ((bb >= 0.0f) ? -1 : -2);
  mword[b * NALL + i] = cc | ((val + 2) << 8);
}

// ---------------- shfl-based block inclusive scan (TS=512, 8 waves) ----------
__device__ __forceinline__ int block_incl_scan(int v, int tid, int* wsum) {
  __syncthreads();  // protect wsum reuse across consecutive calls
  int s = v;
  #pragma unroll
  for (int off = 1; off < 64; off <<= 1) {
    int u = __shfl_up(s, off);
    if ((tid & 63) >= off) s += u;
  }
  const int wid = tid >> 6;
  if ((tid & 63) == 63) wsum[wid] = s;
  __syncthreads();
  if (wid == 0) {
    const int lane = tid & 63;
    int w = (lane < (TS >> 6)) ? wsum[lane] : 0;
    #pragma unroll
    for (int off = 1; off < (TS >> 6); off <<= 1) {
      int u = __shfl_up(w, off);
      if (lane >= off) w += u;
    }
    if (lane < (TS >> 6)) wsum[lane] = w;
  }
  __syncthreads();
  return s + (wid ? wsum[wid - 1] : 0);
}

// ---------------- Kernel 2: balanced sampling + ordering + gather ----------------
// One block of 512 threads per batch. Both phases share ONE packed u32
// histogram (pos counts in bits 0-15, neg in bits 16-31; totals <= 8320 so
// fields never carry) -> one element pass + one packed suffix scan. Per-
// element bin/code/score live in statically-indexed register arrays. The
// two boundary-bin sorts run concurrently in different waves.
__global__ __launch_bounds__(TS) void k_select(
    const int* __restrict__ mword,
    const float* __restrict__ noise,  // B,NALL,2
    const float* __restrict__ rois,
    const float* __restrict__ gt,
    const float* __restrict__ gtcls,  // B,NGT,1
    float* __restrict__ out)
{
  #pragma clang fp contract(off)
  const int b = blockIdx.x;
  const int tid = threadIdx.x;

  __shared__ int hist[1024];            // packed pos|neg<<16
  __shared__ int wsum[TS >> 6];
  __shared__ int s_total;               // packed totals
  __shared__ float bval[2][BCAP];
  __shared__ int bidx_[2][BCAP];
  __shared__ int bcnt[2];
  __shared__ int s_bstar[2], s_need[2];
  __shared__ unsigned char ind[NALL];
  __shared__ unsigned short sorder[NSAMP];

  int ew[CH];     // code | (bin<<2), 0 if not a candidate
  float fv[CH];   // candidate's noise score

  hist[tid] = 0;
  hist[tid + TS] = 0;
  if (tid < 2) bcnt[tid] = 0;

  // ---- single pass: codes + bins + packed histogram + ind init ----
  #pragma unroll
  for (int k = 0; k < CH; ++k) {
    const int i = tid + k * TS;
    int w = 0;
    float v = 0.0f;
    if (i < NALL) {
      ind[i] = 0;
      const int code = (mword[b * NALL + i] >> 8) & 3;
      if (code == 3 || code == 1) {
        float2 nz = reinterpret_cast<const float2*>(noise)[b * NALL + i];
        v = (code == 3) ? nz.x : nz.y;
        int bin = (int)(v * 1024.0f);
        bin = bin < 0 ? 0 : (bin > 1023 ? 1023 : bin);
        w = code | (bin << 2);
      }
    }
    ew[k] = w;
    fv[k] = v;
  }
  __syncthreads();
  #pragma unroll
  for (int k = 0; k < CH; ++k) {
    const int w = ew[k];
    if (w) atomicAdd(&hist[w >> 2], ((w & 3) == 3) ? 1 : (1 << 16));
  }
  __syncthreads();

  // ---- one packed suffix scan over 1024 bins (thread t owns 2t, 2t+1) ----
  const int c0 = hist[2 * tid], c1 = hist[2 * tid + 1];
  const int incl = block_incl_scan(c0 + c1, tid, wsum);
  if (tid == TS - 1) s_total = incl;
  __syncthreads();
  const int total = s_total;

  #pragma unroll
  for (int p = 0; p < 2; ++p) {
    const int want = p ? KNEG : KPOS;
    const int sh = p ? 16 : 0;
    const int tot = (total >> sh) & 0xFFFF;
    if (tot >= want) {                              // !selall
      const int inc = (incl >> sh) & 0xFFFF;
      const int ah = tot - inc;                     // sum of bins > 2t+1
      const int f0 = (c0 >> sh) & 0xFFFF;
      const int f1 = (c1 >> sh) & 0xFFFF;
      if (ah + f0 + f1 >= want && ah < want) {      // unique boundary thread
        if (ah + f1 >= want) { s_bstar[p] = 2 * tid + 1; s_need[p] = want - ah; }
        else                 { s_bstar[p] = 2 * tid;     s_need[p] = want - (ah + f1); }
      }
    }
  }
  __syncthreads();

  const int totP = total & 0xFFFF, totN = (total >> 16) & 0xFFFF;
  const bool selall0 = (totP < KPOS), selall1 = (totN < KNEG);

  // ---- mark: bins above boundary selected; boundary bins collected ----
  #pragma unroll
  for (int k = 0; k < CH; ++k) {
    const int w = ew[k];
    if (w) {
      const int i = tid + k * TS;
      const int p = ((w & 3) == 3) ? 0 : 1;
      const bool selall = p ? selall1 : selall0;
      const int bin = w >> 2;
      if (selall || bin > s_bstar[p]) {
        ind[i] = 1;
      } else if (bin == s_bstar[p]) {
        int pos = atomicAdd(&bcnt[p], 1);
        if (pos < BCAP) { bval[p][pos] = fv[k]; bidx_[p][pos] = i; }
      }
    }
  }
  __syncthreads();

  // ---- boundary-bin exact sorts, concurrent in two waves ----
  if ((tid == 0 && !selall0) || (tid == 64 && !selall1)) {
    const int p = (tid == 0) ? 0 : 1;
    int cnt = bcnt[p]; if (cnt > BCAP) cnt = BCAP;
    float* bv = bval[p]; int* bi = bidx_[p];
    for (int x = 1; x < cnt; ++x) {
      float v = bv[x]; int id = bi[x];
      int y = x - 1;
      while (y >= 0 && (bv[y] < v || (bv[y] == v && bi[y] > id))) {
        bv[y + 1] = bv[y]; bi[y + 1] = bi[y]; --y;
      }
      bv[y + 1] = v; bi[y + 1] = id;
    }
    int need = s_need[p]; if (need > cnt) need = cnt;
    for (int x = 0; x < need; ++x) ind[bi[x]] = 1;
  }
  __syncthreads();

  // ---- ordering: ones ascending then zeros ascending (top_k of 0/1) ----
  const int C = CH;
  const int start = tid * C;
  const int end = (start + C < NALL) ? (start + C) : NALL;
  int cnt1 = 0;
  for (int i = start; i < end; ++i) cnt1 += ind[i];
  const int incl1 = block_incl_scan(cnt1, tid, wsum);
  if (tid == TS - 1) s_total = incl1;
  __syncthreads();
  const int K1 = s_total;
  int ones_before = incl1 - cnt1;
  const int nzero = NSAMP - K1;
  for (int i = start; i < end; ++i) {
    if (ind[i]) {
      sorder[ones_before] = (unsigned short)i;
      ones_before++;
    } else {
      const int zrank = i - ones_before;
      if (zrank < nzero) sorder[K1 + zrank] = (unsigned short)i;
    }
  }
  __syncthreads();

  // ---- fused gather + encode + write (one sample per thread) ----
  {
    const int s = tid;
    const int idx = sorder[s];
    const size_t t = (size_t)b * NSAMP + s;

    float4 A = (idx < NROIS)
      ? reinterpret_cast<const float4*>(rois)[b * NROIS + idx]
      : reinterpret_cast<const float4*>(gt)[b * NGT + (idx - NROIS)];

    const int w = mword[b * NALL + idx];
    const int col = w & 0xFF;
    const bool pos = (((w >> 8) & 3) == 3);

    float e0 = 0.f, e1 = 0.f, e2 = 0.f, e3 = 0.f, cls = 0.f;
    if (pos) {
      float4 G = reinterpret_cast<const float4*>(gt)[b * NGT + col];
      float ah = A.z - A.x, aw = A.w - A.y;
      float acy = A.x + 0.5f * ah, acx = A.y + 0.5f * aw;
      float bh = G.z - G.x, bw = G.w - G.y;
      float bcy = G.x + 0.5f * bh, bcx = G.y + 0.5f * bw;
      e0 = ((bcy - acy) / ah) / 0.1f;
      e1 = ((bcx - acx) / aw) / 0.1f;
      e2 = logf(bh / ah) / 0.2f;
      e3 = logf(bw / aw) / 0.2f;
      cls = gtcls[b * NGT + col];
    }

    float* o_rois = out;                           // NB*NSAMP*4
    float* o_enc  = out + (size_t)NB * NSAMP * 4;  // NB*NSAMP*4
    float* o_bw   = out + (size_t)NB * NSAMP * 8;
    float* o_cls  = o_bw + (size_t)NB * NSAMP;
    float* o_cw   = o_cls + (size_t)NB * NSAMP;

    reinterpret_cast<float4*>(o_rois)[t] = A;
    float4 E; E.x = e0; E.y = e1; E.z = e2; E.w = e3;
    reinterpret_cast<float4*>(o_enc)[t] = E;
    o_bw[t]  = pos ? 1.0f : 0.0f;
    o_cls[t] = cls;
    o_cw[t]  = (s < K1) ? 1.0f : 0.0f;
  }
}

extern "C" void kernel_launch(void* const* d_in, const int* in_sizes, int n_in,
                              void* d_out, int out_size, void* d_ws, size_t ws_size,
                              hipStream_t stream) {
  const float* rois  = (const float*)d_in[0];
  const float* gt    = (const float*)d_in[1];
  const float* gtcls = (const float*)d_in[2];
  const float* noise = (const float*)d_in[3];
  float* out = (float*)d_out;

  int* mword = (int*)d_ws;  // NB*NALL ints

  dim3 g1((NALL + 255) / 256, NB);  // (33, 32) = 1056 blocks
  k_match<<<g1, 256, 0, stream>>>(rois, gt, mword);
  k_select<<<NB, TS, 0, stream>>>(mword, noise, rois, gt, gtcls, out);
}

// Round 5
// 51.135 us; speedup vs baseline: 2.0046x; 1.1496x over previous
//
#include <hip/hip_runtime.h>
#include <cstdint>

#define NB 32
#define NROIS 8192
#define NGT 128
#define NALL (NROIS + NGT)   // 8320
#define NSAMP 512
#define KPOS 128
#define KNEG 384
#define BCAP 1024
#define TS 1024              // k_select threads (16 waves)
#define CH 9                 // ceil(NALL/TS)
#define JC 4                 // independent gt chains per thread (ILP)
#define JL 16                // 64 gts per half / JC chains

// ---------------- Kernel 1: IoU matching ----------------
// Each roi's 128 gts are split across 2 threads (64 each) -> 8320 waves
// (~100% occupancy) with an LDS merge. gt boxes are read with wave-uniform
// addresses straight from global (compiler scalarizes to s_load_dwordx4),
// so only the area (1 ds_read_b32) touches LDS per pair. Mask handling
// hoisted to a never-taken slow path. IEEE div + contract(off) keeps iou
// bit-exact vs the numpy reference.
template <bool MASKED>
__device__ __forceinline__ void match_half(
    const float4* __restrict__ gt4b, const float* __restrict__ sab,
    const unsigned char* __restrict__ smk,
    const int half, const float4 A, const float aar, const bool ma,
    float* best, int* bcol)
{
  #pragma clang fp contract(off)
  #pragma unroll 4
  for (int jj = 0; jj < JL; ++jj) {
    #pragma unroll
    for (int c = 0; c < JC; ++c) {
      const int j = half * 64 + c * JL + jj;
      const float4 g = gt4b[j];      // wave-uniform -> scalar load
      const float ab = sab[j];       // LDS b32 (broadcast)
      float iy = fmaxf(fminf(A.z, g.z) - fmaxf(A.x, g.x), 0.0f);
      float ix = fmaxf(fminf(A.w, g.w) - fmaxf(A.y, g.y), 0.0f);
      float inter = iy * ix;
      float uni = (aar + ab) - inter;
      float iou = inter / fmaxf(uni, 1e-8f);
      if (MASKED) { if (ma || (smk[j] != 0)) iou = -1.0f; }
      if (iou > best[c]) { best[c] = iou; bcol[c] = j; }  // first-max in-chain
    }
  }
}

__global__ __launch_bounds__(256) void k_match(
    const float* __restrict__ rois,   // B,NROIS,4
    const float* __restrict__ gt,     // B,NGT,4
    int* __restrict__ mword)          // B*NALL : bits0-7 col, bits8-9 val+2
{
  #pragma clang fp contract(off)
  __shared__ float sab[NGT];           // gt areas
  __shared__ unsigned char smk[NGT];   // masked flag (slow path only)
  __shared__ int s_anymask;
  __shared__ float mbest[128];
  __shared__ int mcol[128];

  const int b = blockIdx.y;
  const int tid = threadIdx.x;
  const float4* gt4b = reinterpret_cast<const float4*>(gt) + b * NGT;

  bool mflag = false;
  if (tid < NGT) {
    float4 g = gt4b[tid];
    sab[tid] = (g.z - g.x) * (g.w - g.y);
    mflag = (g.x == -1.0f) && (g.y == -1.0f) && (g.z == -1.0f) && (g.w == -1.0f);
    smk[tid] = mflag;
  }
  if (tid == 0) s_anymask = 0;
  __syncthreads();
  if (mflag) atomicOr(&s_anymask, 1);
  __syncthreads();

  const int r = tid & 127;
  const int half = tid >> 7;           // waves 0-1: half 0, waves 2-3: half 1
  const int i = blockIdx.x * 128 + r;  // 65*128 == NALL exactly

  float4 A = (i < NROIS)               // block-uniform branch
    ? reinterpret_cast<const float4*>(rois)[b * NROIS + i]
    : gt4b[i - NROIS];
  const float aar = (A.z - A.x) * (A.w - A.y);
  const bool ma = (A.x == -1.0f) && (A.y == -1.0f) && (A.z == -1.0f) && (A.w == -1.0f);

  float best[JC];
  int bcol[JC];
  #pragma unroll
  for (int c = 0; c < JC; ++c) { best[c] = -3.0e38f; bcol[c] = half * 64 + c * JL; }

  if (s_anymask == 0 && __ballot(ma) == 0ULL) {
    match_half<false>(gt4b, sab, smk, half, A, aar, ma, best, bcol);
  } else {
    match_half<true>(gt4b, sab, smk, half, A, aar, ma, best, bcol);
  }

  float bb = best[0];
  int cc = bcol[0];
  #pragma unroll
  for (int c = 1; c < JC; ++c) {
    if (best[c] > bb) { bb = best[c]; cc = bcol[c]; }   // lower chain wins ties
  }

  if (half) { mbest[r] = bb; mcol[r] = cc; }
  __syncthreads();
  if (!half) {
    const float b1 = mbest[r];
    if (b1 > bb) { bb = b1; cc = mcol[r]; }             // half0 (lower j) wins ties
    int val = (bb >= 0.5f) ? 1 : ((bb >= 0.0f) ? -1 : -2);
    mword[b * NALL + i] = cc | ((val + 2) << 8);
  }
}

// ---------------- shfl-based block inclusive scan (TS=1024, 16 waves) -------
__device__ __forceinline__ int block_incl_scan(int v, int tid, int* wsum) {
  __syncthreads();  // protect wsum reuse across consecutive calls
  int s = v;
  #pragma unroll
  for (int off = 1; off < 64; off <<= 1) {
    int u = __shfl_up(s, off);
    if ((tid & 63) >= off) s += u;
  }
  const int wid = tid >> 6;
  if ((tid & 63) == 63) wsum[wid] = s;
  __syncthreads();
  if (wid == 0) {
    const int lane = tid & 63;
    int w = (lane < (TS >> 6)) ? wsum[lane] : 0;
    #pragma unroll
    for (int off = 1; off < (TS >> 6); off <<= 1) {
      int u = __shfl_up(w, off);
      if (lane >= off) w += u;
    }
    if (lane < (TS >> 6)) wsum[lane] = w;
  }
  __syncthreads();
  return s + (wid ? wsum[wid - 1] : 0);
}

// ---------------- Kernel 2: balanced sampling + ordering + gather ------------
// One block of 1024 threads per batch. One packed u32 histogram serves both
// phases (pos | neg<<16); one packed suffix scan with one bin per thread
// finds both boundary bins; boundary-bin exact top-k via block-parallel rank
// selection (value desc, index asc). Element passes are CH=9 long.
__global__ __launch_bounds__(TS) void k_select(
    const int* __restrict__ mword,
    const float* __restrict__ noise,  // B,NALL,2
    const float* __restrict__ rois,
    const float* __restrict__ gt,
    const float* __restrict__ gtcls,  // B,NGT,1
    float* __restrict__ out)
{
  #pragma clang fp contract(off)
  const int b = blockIdx.x;
  const int tid = threadIdx.x;

  __shared__ int hist[1024];            // packed pos|neg<<16
  __shared__ int wsum[TS >> 6];
  __shared__ int s_total;               // packed totals
  __shared__ float bval[2][BCAP];
  __shared__ int bidx_[2][BCAP];
  __shared__ int bcnt[2];
  __shared__ int s_bstar[2], s_need[2];
  __shared__ unsigned char ind[NALL];
  __shared__ unsigned short sorder[NSAMP];

  int ew[CH];     // code | (bin<<2), 0 if not a candidate
  float fv[CH];   // candidate's noise score

  hist[tid] = 0;
  if (tid < 2) bcnt[tid] = 0;

  // ---- single pass: codes + bins + ind init ----
  #pragma unroll
  for (int k = 0; k < CH; ++k) {
    const int i = tid + k * TS;
    int w = 0;
    float v = 0.0f;
    if (i < NALL) {
      ind[i] = 0;
      const int code = (mword[b * NALL + i] >> 8) & 3;
      if (code == 3 || code == 1) {
        float2 nz = reinterpret_cast<const float2*>(noise)[b * NALL + i];
        v = (code == 3) ? nz.x : nz.y;
        int bin = (int)(v * 1024.0f);
        bin = bin < 0 ? 0 : (bin > 1023 ? 1023 : bin);
        w = code | (bin << 2);
      }
    }
    ew[k] = w;
    fv[k] = v;
  }
  __syncthreads();
  #pragma unroll
  for (int k = 0; k < CH; ++k) {
    const int w = ew[k];
    if (w) atomicAdd(&hist[w >> 2], ((w & 3) == 3) ? 1 : (1 << 16));
  }
  __syncthreads();

  // ---- packed suffix scan, one bin per thread ----
  const int c = hist[tid];
  const int incl = block_incl_scan(c, tid, wsum);
  if (tid == TS - 1) s_total = incl;
  __syncthreads();
  const int total = s_total;

  #pragma unroll
  for (int p = 0; p < 2; ++p) {
    const int want = p ? KNEG : KPOS;
    const int sh = p ? 16 : 0;
    const int tot = (total >> sh) & 0xFFFF;
    if (tot >= want) {                              // !selall
      const int inc = (incl >> sh) & 0xFFFF;
      const int cp = (c >> sh) & 0xFFFF;
      const int above = tot - inc;                  // sum of bins > tid
      if (above < want && above + cp >= want) {     // unique boundary thread
        s_bstar[p] = tid; s_need[p] = want - above;
      }
    }
  }
  __syncthreads();

  const bool selall0 = ((total & 0xFFFF) < KPOS);
  const bool selall1 = (((total >> 16) & 0xFFFF) < KNEG);

  // ---- mark: bins above boundary selected; boundary bins collected ----
  #pragma unroll
  for (int k = 0; k < CH; ++k) {
    const int w = ew[k];
    if (w) {
      const int i = tid + k * TS;
      const int p = ((w & 3) == 3) ? 0 : 1;
      const bool selall = p ? selall1 : selall0;
      const int bin = w >> 2;
      if (selall || bin > s_bstar[p]) {
        ind[i] = 1;
      } else if (bin == s_bstar[p]) {
        int pos = atomicAdd(&bcnt[p], 1);
        if (pos < BCAP) { bval[p][pos] = fv[k]; bidx_[p][pos] = i; }
      }
    }
  }
  __syncthreads();

  // ---- boundary-bin exact top-k via parallel rank (value desc, idx asc) ----
  #pragma unroll
  for (int p = 0; p < 2; ++p) {
    const bool selall = p ? selall1 : selall0;
    if (selall) continue;
    int cnt = bcnt[p]; if (cnt > BCAP) cnt = BCAP;
    const int need = s_need[p];
    for (int x = tid; x < cnt; x += TS) {
      const float v = bval[p][x];
      const int id = bidx_[p][x];
      int rank = 0;
      for (int y = 0; y < cnt; ++y) {
        const float vy = bval[p][y];
        const int iy2 = bidx_[p][y];
        rank += (vy > v) || (vy == v && iy2 < id);
      }
      if (rank < need) ind[id] = 1;
    }
  }
  __syncthreads();

  // ---- ordering: ones ascending then zeros ascending (top_k of 0/1) ----
  const int start = tid * CH;
  const int end = (start + CH < NALL) ? (start + CH) : NALL;
  int cnt1 = 0;
  for (int i = start; i < end; ++i) cnt1 += ind[i];
  const int incl1 = block_incl_scan(cnt1, tid, wsum);
  if (tid == TS - 1) s_total = incl1;
  __syncthreads();
  const int K1 = s_total;
  int ones_before = incl1 - cnt1;
  const int nzero = NSAMP - K1;
  for (int i = start; i < end; ++i) {
    if (ind[i]) {
      sorder[ones_before] = (unsigned short)i;
      ones_before++;
    } else {
      const int zrank = i - ones_before;
      if (zrank < nzero) sorder[K1 + zrank] = (unsigned short)i;
    }
  }
  __syncthreads();

  // ---- fused gather + encode + write (one sample per thread) ----
  if (tid < NSAMP) {
    const int s = tid;
    const int idx = sorder[s];
    const size_t t = (size_t)b * NSAMP + s;

    float4 A = (idx < NROIS)
      ? reinterpret_cast<const float4*>(rois)[b * NROIS + idx]
      : reinterpret_cast<const float4*>(gt)[b * NGT + (idx - NROIS)];

    const int w = mword[b * NALL + idx];
    const int col = w & 0xFF;
    const bool pos = (((w >> 8) & 3) == 3);

    float e0 = 0.f, e1 = 0.f, e2 = 0.f, e3 = 0.f, cls = 0.f;
    if (pos) {
      float4 G = reinterpret_cast<const float4*>(gt)[b * NGT + col];
      float ah = A.z - A.x, aw = A.w - A.y;
      float acy = A.x + 0.5f * ah, acx = A.y + 0.5f * aw;
      float bh = G.z - G.x, bw = G.w - G.y;
      float bcy = G.x + 0.5f * bh, bcx = G.y + 0.5f * bw;
      e0 = ((bcy - acy) / ah) / 0.1f;
      e1 = ((bcx - acx) / aw) / 0.1f;
      e2 = logf(bh / ah) / 0.2f;
      e3 = logf(bw / aw) / 0.2f;
      cls = gtcls[b * NGT + col];
    }

    float* o_rois = out;                           // NB*NSAMP*4
    float* o_enc  = out + (size_t)NB * NSAMP * 4;  // NB*NSAMP*4
    float* o_bw   = out + (size_t)NB * NSAMP * 8;
    float* o_cls  = o_bw + (size_t)NB * NSAMP;
    float* o_cw   = o_cls + (size_t)NB * NSAMP;

    reinterpret_cast<float4*>(o_rois)[t] = A;
    float4 E; E.x = e0; E.y = e1; E.z = e2; E.w = e3;
    reinterpret_cast<float4*>(o_enc)[t] = E;
    o_bw[t]  = pos ? 1.0f : 0.0f;
    o_cls[t] = cls;
    o_cw[t]  = (s < K1) ? 1.0f : 0.0f;
  }
}

extern "C" void kernel_launch(void* const* d_in, const int* in_sizes, int n_in,
                              void* d_out, int out_size, void* d_ws, size_t ws_size,
                              hipStream_t stream) {
  const float* rois  = (const float*)d_in[0];
  const float* gt    = (const float*)d_in[1];
  const float* gtcls = (const float*)d_in[2];
  const float* noise = (const float*)d_in[3];
  float* out = (float*)d_out;

  int* mword = (int*)d_ws;  // NB*NALL ints

  dim3 g1(NALL / 128, NB);  // (65, 32) = 2080 blocks, 4 waves each
  k_match<<<g1, 256, 0, stream>>>(rois, gt, mword);
  k_select<<<NB, TS, 0, stream>>>(mword, noise, rois, gt, gtcls, out);
}

// Round 6
// 44.658 us; speedup vs baseline: 2.2953x; 1.1450x over previous
//
#include <hip/hip_runtime.h>
#include <cstdint>

#define NB 32
#define NROIS 8192
#define NGT 128
#define NALL (NROIS + NGT)   // 8320
#define NSAMP 512
#define KPOS 128
#define KNEG 384
#define BCAP 1024
#define TS 1024              // k_select threads (16 waves)
#define CH 9                 // ceil(NALL/TS)
#define JC 4                 // independent gt chains per thread (ILP)
#define JL 16                // 64 gts per half / JC chains

// ---------------- Kernel 1: IoU matching + bin fusion ----------------
// Each roi's 128 gts split across 2 threads (64 each) -> 8320 waves (~full
// residency), LDS merge at the end. gt boxes + areas staged in LDS
// (broadcast ds_read_b128/b32 - LDS pipe runs parallel to the VALU-bound
// pair math). Mask handling hoisted to a never-taken slow path. Epilogue
// also computes the sampling bin from noise (work moved out of k_select)
// and packs col|code<<7|bin<<9 into one word. IEEE div + contract(off)
// keeps iou bit-exact vs the numpy reference.
template <bool MASKED>
__device__ __forceinline__ void match_half(
    const float4* __restrict__ sg, const float* __restrict__ sab,
    const unsigned char* __restrict__ smk,
    const int half, const float4 A, const float aar, const bool ma,
    float* best, int* bcol)
{
  #pragma clang fp contract(off)
  const int jb = half * 64;
  #pragma unroll 4
  for (int jj = 0; jj < JL; ++jj) {
    #pragma unroll
    for (int c = 0; c < JC; ++c) {
      const int j = jb + c * JL + jj;
      const float4 g = sg[j];        // LDS broadcast b128
      const float ab = sab[j];       // LDS broadcast b32
      float iy = fmaxf(fminf(A.z, g.z) - fmaxf(A.x, g.x), 0.0f);
      float ix = fmaxf(fminf(A.w, g.w) - fmaxf(A.y, g.y), 0.0f);
      float inter = iy * ix;
      float uni = (aar + ab) - inter;
      float iou = inter / fmaxf(uni, 1e-8f);
      if (MASKED) { if (ma || (smk[j] != 0)) iou = -1.0f; }
      if (iou > best[c]) { best[c] = iou; bcol[c] = j; }  // first-max in-chain
    }
  }
}

__global__ __launch_bounds__(256) void k_match(
    const float* __restrict__ rois,   // B,NROIS,4
    const float* __restrict__ gt,     // B,NGT,4
    const float* __restrict__ noise,  // B,NALL,2
    int* __restrict__ mword)          // B*NALL : col | code<<7 | bin<<9
{
  #pragma clang fp contract(off)
  __shared__ float4 sg[NGT];
  __shared__ float sab[NGT];           // gt areas
  __shared__ unsigned char smk[NGT];   // masked flag (slow path only)
  __shared__ int s_anymask;
  __shared__ float mbest[128];
  __shared__ int mcol[128];

  const int b = blockIdx.y;
  const int tid = threadIdx.x;

  bool mflag = false;
  if (tid < NGT) {
    float4 g = reinterpret_cast<const float4*>(gt)[b * NGT + tid];
    sg[tid] = g;
    sab[tid] = (g.z - g.x) * (g.w - g.y);
    mflag = (g.x == -1.0f) && (g.y == -1.0f) && (g.z == -1.0f) && (g.w == -1.0f);
    smk[tid] = mflag;
  }
  if (tid == 0) s_anymask = 0;
  __syncthreads();
  if (mflag) atomicOr(&s_anymask, 1);
  __syncthreads();

  const int r = tid & 127;
  const int half = tid >> 7;           // waves 0-1: half 0, waves 2-3: half 1
  const int i = blockIdx.x * 128 + r;  // 65*128 == NALL exactly

  float4 A = (i < NROIS)               // block-uniform branch
    ? reinterpret_cast<const float4*>(rois)[b * NROIS + i]
    : sg[i - NROIS];
  const float aar = (A.z - A.x) * (A.w - A.y);
  const bool ma = (A.x == -1.0f) && (A.y == -1.0f) && (A.z == -1.0f) && (A.w == -1.0f);

  float best[JC];
  int bcol[JC];
  #pragma unroll
  for (int c = 0; c < JC; ++c) { best[c] = -3.0e38f; bcol[c] = half * 64 + c * JL; }

  if (s_anymask == 0 && __ballot(ma) == 0ULL) {
    match_half<false>(sg, sab, smk, half, A, aar, ma, best, bcol);
  } else {
    match_half<true>(sg, sab, smk, half, A, aar, ma, best, bcol);
  }

  float bb = best[0];
  int cc = bcol[0];
  #pragma unroll
  for (int c = 1; c < JC; ++c) {
    if (best[c] > bb) { bb = best[c]; cc = bcol[c]; }   // lower chain wins ties
  }

  if (half) { mbest[r] = bb; mcol[r] = cc; }
  __syncthreads();
  if (!half) {
    const float b1 = mbest[r];
    if (b1 > bb) { bb = b1; cc = mcol[r]; }             // half0 (lower j) wins ties
    const int code = (bb >= 0.5f) ? 3 : ((bb >= 0.0f) ? 1 : 0);
    // fused sampling-bin computation (identical formula to the old k_select)
    float2 nz = reinterpret_cast<const float2*>(noise)[b * NALL + i];
    float v = (code == 3) ? nz.x : nz.y;
    int bin = (int)(v * 1024.0f);
    bin = bin < 0 ? 0 : (bin > 1023 ? 1023 : bin);
    mword[b * NALL + i] = cc | (code << 7) | (bin << 9);
  }
}

// ---------------- shfl-based block inclusive scan (TS=1024, 16 waves) -------
__device__ __forceinline__ int block_incl_scan(int v, int tid, int* wsum) {
  __syncthreads();  // protect wsum reuse across consecutive calls
  int s = v;
  #pragma unroll
  for (int off = 1; off < 64; off <<= 1) {
    int u = __shfl_up(s, off);
    if ((tid & 63) >= off) s += u;
  }
  const int wid = tid >> 6;
  if ((tid & 63) == 63) wsum[wid] = s;
  __syncthreads();
  if (wid == 0) {
    const int lane = tid & 63;
    int w = (lane < (TS >> 6)) ? wsum[lane] : 0;
    #pragma unroll
    for (int off = 1; off < (TS >> 6); off <<= 1) {
      int u = __shfl_up(w, off);
      if (lane >= off) w += u;
    }
    if (lane < (TS >> 6)) wsum[lane] = w;
  }
  __syncthreads();
  return s + (wid ? wsum[wid - 1] : 0);
}

// ---------------- Kernel 2: balanced sampling + ordering + gather ------------
// One block of 1024 threads per batch. Pass 1 reads ONE precomputed int per
// element (code+bin fused upstream in k_match). One packed u32 histogram
// serves both phases (pos | neg<<16); one packed suffix scan finds both
// boundary bins; boundary-bin exact top-k via block-parallel rank selection
// (value desc, index asc) with noise reloaded only for those few elements.
__global__ __launch_bounds__(TS) void k_select(
    const int* __restrict__ mword,
    const float* __restrict__ noise,  // B,NALL,2
    const float* __restrict__ rois,
    const float* __restrict__ gt,
    const float* __restrict__ gtcls,  // B,NGT,1
    float* __restrict__ out)
{
  #pragma clang fp contract(off)
  const int b = blockIdx.x;
  const int tid = threadIdx.x;

  __shared__ int hist[1024];            // packed pos|neg<<16
  __shared__ int wsum[TS >> 6];
  __shared__ int s_total;               // packed totals
  __shared__ float bval[2][BCAP];
  __shared__ int bidx_[2][BCAP];
  __shared__ int bcnt[2];
  __shared__ int s_bstar[2], s_need[2];
  __shared__ unsigned char ind[NALL];
  __shared__ unsigned short sorder[NSAMP];

  int ew[CH];     // packed word; bit7 set => candidate

  hist[tid] = 0;
  if (tid < 2) bcnt[tid] = 0;

  // ---- pass 1: one int load per element; histogram + ind init ----
  #pragma unroll
  for (int k = 0; k < CH; ++k) {
    const int i = tid + k * TS;
    int w = 0;
    if (i < NALL) {
      ind[i] = 0;
      w = mword[b * NALL + i];
    }
    ew[k] = w;
  }
  __syncthreads();
  #pragma unroll
  for (int k = 0; k < CH; ++k) {
    const int w = ew[k];
    if (w & 0x80) atomicAdd(&hist[w >> 9], (w & 0x100) ? 1 : (1 << 16));
  }
  __syncthreads();

  // ---- packed suffix scan, one bin per thread ----
  const int c = hist[tid];
  const int incl = block_incl_scan(c, tid, wsum);
  if (tid == TS - 1) s_total = incl;
  __syncthreads();
  const int total = s_total;

  #pragma unroll
  for (int p = 0; p < 2; ++p) {
    const int want = p ? KNEG : KPOS;
    const int sh = p ? 16 : 0;
    const int tot = (total >> sh) & 0xFFFF;
    if (tot >= want) {                              // !selall
      const int inc = (incl >> sh) & 0xFFFF;
      const int cp = (c >> sh) & 0xFFFF;
      const int above = tot - inc;                  // sum of bins > tid
      if (above < want && above + cp >= want) {     // unique boundary thread
        s_bstar[p] = tid; s_need[p] = want - above;
      }
    }
  }
  __syncthreads();

  const bool selall0 = ((total & 0xFFFF) < KPOS);
  const bool selall1 = (((total >> 16) & 0xFFFF) < KNEG);

  // ---- mark: bins above boundary selected; boundary bins collected ----
  #pragma unroll
  for (int k = 0; k < CH; ++k) {
    const int w = ew[k];
    if (w & 0x80) {
      const int i = tid + k * TS;
      const int p = (w & 0x100) ? 0 : 1;
      const bool selall = p ? selall1 : selall0;
      const int bin = w >> 9;
      if (selall || bin > s_bstar[p]) {
        ind[i] = 1;
      } else if (bin == s_bstar[p]) {
        int pos = atomicAdd(&bcnt[p], 1);
        if (pos < BCAP) {
          bval[p][pos] = noise[((size_t)(b * NALL + i)) * 2 + p];  // rare reload
          bidx_[p][pos] = i;
        }
      }
    }
  }
  __syncthreads();

  // ---- boundary-bin exact top-k via parallel rank (value desc, idx asc) ----
  #pragma unroll
  for (int p = 0; p < 2; ++p) {
    const bool selall = p ? selall1 : selall0;
    if (selall) continue;
    int cnt = bcnt[p]; if (cnt > BCAP) cnt = BCAP;
    const int need = s_need[p];
    for (int x = tid; x < cnt; x += TS) {
      const float v = bval[p][x];
      const int id = bidx_[p][x];
      int rank = 0;
      for (int y = 0; y < cnt; ++y) {
        const float vy = bval[p][y];
        const int iy2 = bidx_[p][y];
        rank += (vy > v) || (vy == v && iy2 < id);
      }
      if (rank < need) ind[id] = 1;
    }
  }
  __syncthreads();

  // ---- ordering: ones ascending then zeros ascending (top_k of 0/1) ----
  const int start = tid * CH;
  const int end = (start + CH < NALL) ? (start + CH) : NALL;
  int cnt1 = 0;
  for (int i = start; i < end; ++i) cnt1 += ind[i];
  const int incl1 = block_incl_scan(cnt1, tid, wsum);
  if (tid == TS - 1) s_total = incl1;
  __syncthreads();
  const int K1 = s_total;
  int ones_before = incl1 - cnt1;
  const int nzero = NSAMP - K1;
  for (int i = start; i < end; ++i) {
    if (ind[i]) {
      sorder[ones_before] = (unsigned short)i;
      ones_before++;
    } else {
      const int zrank = i - ones_before;
      if (zrank < nzero) sorder[K1 + zrank] = (unsigned short)i;
    }
  }
  __syncthreads();

  // ---- fused gather + encode + write (one sample per thread) ----
  if (tid < NSAMP) {
    const int s = tid;
    const int idx = sorder[s];
    const size_t t = (size_t)b * NSAMP + s;

    float4 A = (idx < NROIS)
      ? reinterpret_cast<const float4*>(rois)[b * NROIS + idx]
      : reinterpret_cast<const float4*>(gt)[b * NGT + (idx - NROIS)];

    const int w = mword[b * NALL + idx];
    const int col = w & 0x7F;
    const bool pos = (((w >> 7) & 3) == 3);

    float e0 = 0.f, e1 = 0.f, e2 = 0.f, e3 = 0.f, cls = 0.f;
    if (pos) {
      float4 G = reinterpret_cast<const float4*>(gt)[b * NGT + col];
      float ah = A.z - A.x, aw = A.w - A.y;
      float acy = A.x + 0.5f * ah, acx = A.y + 0.5f * aw;
      float bh = G.z - G.x, bw = G.w - G.y;
      float bcy = G.x + 0.5f * bh, bcx = G.y + 0.5f * bw;
      e0 = ((bcy - acy) / ah) / 0.1f;
      e1 = ((bcx - acx) / aw) / 0.1f;
      e2 = logf(bh / ah) / 0.2f;
      e3 = logf(bw / aw) / 0.2f;
      cls = gtcls[b * NGT + col];
    }

    float* o_rois = out;                           // NB*NSAMP*4
    float* o_enc  = out + (size_t)NB * NSAMP * 4;  // NB*NSAMP*4
    float* o_bw   = out + (size_t)NB * NSAMP * 8;
    float* o_cls  = o_bw + (size_t)NB * NSAMP;
    float* o_cw   = o_cls + (size_t)NB * NSAMP;

    reinterpret_cast<float4*>(o_rois)[t] = A;
    float4 E; E.x = e0; E.y = e1; E.z = e2; E.w = e3;
    reinterpret_cast<float4*>(o_enc)[t] = E;
    o_bw[t]  = pos ? 1.0f : 0.0f;
    o_cls[t] = cls;
    o_cw[t]  = (s < K1) ? 1.0f : 0.0f;
  }
}

extern "C" void kernel_launch(void* const* d_in, const int* in_sizes, int n_in,
                              void* d_out, int out_size, void* d_ws, size_t ws_size,
                              hipStream_t stream) {
  const float* rois  = (const float*)d_in[0];
  const float* gt    = (const float*)d_in[1];
  const float* gtcls = (const float*)d_in[2];
  const float* noise = (const float*)d_in[3];
  float* out = (float*)d_out;

  int* mword = (int*)d_ws;  // NB*NALL ints

  dim3 g1(NALL / 128, NB);  // (65, 32) = 2080 blocks, 4 waves each
  k_match<<<g1, 256, 0, stream>>>(rois, gt, noise, mword);
  k_select<<<NB, TS, 0, stream>>>(mword, noise, rois, gt, gtcls, out);
}